// Round 3
// baseline (1071.970 us; speedup 1.0000x reference)
//
#include <hip/hip_runtime.h>
#include <float.h>
#include <stdint.h>

// DGCNN_Grouper forward on MI355X. B=8, N=2048, K=16, fp32.
// 3 dispatches: memset(flags+stats) -> megaA (FPS + everything independent,
// overlapped via co-resident worker pool) -> megaB (L2..L4 conv pipeline
// with internal grid barriers).

#define DI __device__ __forceinline__
DI float f_add(float a, float b) { return __fadd_rn(a, b); }
DI float f_sub(float a, float b) { return __fsub_rn(a, b); }
DI float f_mul(float a, float b) { return __fmul_rn(a, b); }

DI uint64_t umax64(uint64_t a, uint64_t b) { return a > b ? a : b; }

DI int imin(int a, int b) { return a < b ? a : b; }

// 6-step gfx9 DPP max-reduce over 64 lanes of a packed u64 key; broadcast via
// readlane 63. Identity 0 safe (real keys always nonzero). Validated round 2.
template<int CTRL, int RMASK>
DI uint64_t dpp_step_max(uint64_t k) {
  uint32_t lo = (uint32_t)__builtin_amdgcn_update_dpp(0, (int)(uint32_t)k,        CTRL, RMASK, 0xF, false);
  uint32_t hi = (uint32_t)__builtin_amdgcn_update_dpp(0, (int)(uint32_t)(k >> 32), CTRL, RMASK, 0xF, false);
  uint64_t o = ((uint64_t)hi << 32) | lo;
  return umax64(k, o);
}
DI uint64_t wave_max_bcast(uint64_t k) {
  k = dpp_step_max<0x111, 0xF>(k);  // row_shr:1
  k = dpp_step_max<0x112, 0xF>(k);  // row_shr:2
  k = dpp_step_max<0x114, 0xF>(k);  // row_shr:4
  k = dpp_step_max<0x118, 0xF>(k);  // row_shr:8
  k = dpp_step_max<0x142, 0xA>(k);  // row_bcast15
  k = dpp_step_max<0x143, 0xC>(k);  // row_bcast31
  uint32_t lo = (uint32_t)__builtin_amdgcn_readlane((int)(uint32_t)k, 63);
  uint32_t hi = (uint32_t)__builtin_amdgcn_readlane((int)(uint32_t)(k >> 32), 63);
  return ((uint64_t)hi << 32) | lo;
}

// ---------------------------------------------------------------------------
// Device-scope sync helpers (all blocks co-resident by construction: grid=256).
// ---------------------------------------------------------------------------
DI void barrier_arrive_wait(int* ctr, int target) {
  __threadfence();
  __syncthreads();
  if (threadIdx.x == 0) {
    __hip_atomic_fetch_add(ctr, 1, __ATOMIC_ACQ_REL, __HIP_MEMORY_SCOPE_AGENT);
    while (__hip_atomic_load(ctr, __ATOMIC_ACQUIRE, __HIP_MEMORY_SCOPE_AGENT) < target)
      __builtin_amdgcn_s_sleep(2);
  }
  __syncthreads();
  __threadfence();
}
DI void wait_flag(const int* ctr, int target) {
  if (threadIdx.x == 0) {
    while (__hip_atomic_load(ctr, __ATOMIC_ACQUIRE, __HIP_MEMORY_SCOPE_AGENT) < target)
      __builtin_amdgcn_s_sleep(2);
  }
  __syncthreads();
  __threadfence();
}
DI void signal_flag(int* ctr) {
  // callers: all global writes done by all block threads; fence+sync first.
  __threadfence();
  __syncthreads();
  if (threadIdx.x == 0)
    __hip_atomic_fetch_add(ctr, 1, __ATOMIC_ACQ_REL, __HIP_MEMORY_SCOPE_AGENT);
}

// ---------------------------------------------------------------------------
// kNN split into stage (keys -> LDS) + queries (4 queries per 256-thr pass).
// Numerics identical to the passing rounds: (qq + rr) - 2*dot, rn ops.
// ---------------------------------------------------------------------------
template<int NKc>
DI void knn_stage(const float* __restrict__ ck, int b, float* smem) {
  float* xs = smem;
  float* ys = smem + NKc;
  float* zs = smem + 2*NKc;
  float* rr = smem + 3*NKc;
  __syncthreads();   // prior readers of smem done
  for (int i = threadIdx.x; i < NKc; i += 256) {
    float a  = ck[((size_t)b*3 + 0)*NKc + i];
    float bb = ck[((size_t)b*3 + 1)*NKc + i];
    float c  = ck[((size_t)b*3 + 2)*NKc + i];
    xs[i] = a; ys[i] = bb; zs[i] = c;
    rr[i] = f_add(f_add(f_mul(a,a), f_mul(bb,bb)), f_mul(c,c));
  }
  __syncthreads();
}

template<int NKc>
DI void knn_queries(const float* __restrict__ cq, int Nq,
                    int* __restrict__ out, int b, int qbase, const float* smem)
{
  constexpr int CPL = NKc / 64;
  const float* xs = smem;
  const float* ys = smem + NKc;
  const float* zs = smem + 2*NKc;
  const float* rr = smem + 3*NKc;
  const int tid = threadIdx.x, lane = tid & 63, w = tid >> 6;
  const int q = qbase + w;
  if (q < Nq) {
    float qx = cq[((size_t)b*3 + 0)*Nq + q];
    float qy = cq[((size_t)b*3 + 1)*Nq + q];
    float qz = cq[((size_t)b*3 + 2)*Nq + q];
    float qq = f_add(f_add(f_mul(qx,qx), f_mul(qy,qy)), f_mul(qz,qz));
    float v[CPL];
    #pragma unroll
    for (int j = 0; j < CPL; ++j) {
      int c = j*64 + lane;
      float dot = f_add(f_add(f_mul(qx,xs[c]), f_mul(qy,ys[c])), f_mul(qz,zs[c]));
      v[j] = f_sub(f_add(qq, rr[c]), f_mul(2.0f, dot));
    }
    unsigned mask = (CPL >= 32) ? 0xFFFFFFFFu : ((1u << CPL) - 1u);
    for (int r = 0; r < 16; ++r) {
      float bv = FLT_MAX; int bc = 0x7FFFFFFF;
      #pragma unroll
      for (int j = 0; j < CPL; ++j) {
        float vj = ((mask >> j) & 1u) ? v[j] : FLT_MAX;
        if (vj < bv) { bv = vj; bc = j*64 + lane; }
      }
      #pragma unroll
      for (int off = 32; off; off >>= 1) {
        float ov = __shfl_xor(bv, off);
        int   oc = __shfl_xor(bc, off);
        if (ov < bv || (ov == bv && oc < bc)) { bv = ov; bc = oc; }
      }
      if ((bc & 63) == lane) mask &= ~(1u << (bc >> 6));
      if (lane == 0) out[((size_t)b*16 + r)*Nq + q] = bc;
    }
  }
}

// ---------------------------------------------------------------------------
// FPS. Level 1: 4 waves, winner lane writes {key, coords} to per-wave slot so
// the next iteration's centroid comes from cndmask selects, not a dependent
// LDS pts[far] read. Parity double-buffered slots; 1 barrier/iter.
// ---------------------------------------------------------------------------
__device__ void fps_body(const float* __restrict__ x, int b,
                         int* __restrict__ s1, float* __restrict__ coorq,
                         int* __restrict__ s2, float* __restrict__ coorq2,
                         float* __restrict__ outc, char* smem_raw, int* flags)
{
  float4*   pts  = (float4*)smem_raw;                    // [2048]
  int*      sel  = (int*)(smem_raw + 32768);             // [512]
  uint64_t* wkey = (uint64_t*)(smem_raw + 32768 + 2048); // [8] (2 parity x 4 waves)
  float4*   wcrd = (float4*)(smem_raw + 32768 + 2048 + 64); // [8]
  const int tid = threadIdx.x, lane = tid & 63, w = tid >> 6;

  for (int i = tid; i < 2048; i += 256)
    pts[i] = make_float4(x[((size_t)b*3 + 0)*2048 + i],
                         x[((size_t)b*3 + 1)*2048 + i],
                         x[((size_t)b*3 + 2)*2048 + i], 0.f);
  __syncthreads();

  float px[8], py[8], pz[8], dl[8];
  #pragma unroll
  for (int j = 0; j < 8; ++j) {
    float4 p = pts[tid + 256*j];
    px[j] = p.x; py[j] = p.y; pz[j] = p.z; dl[j] = 1e10f;
  }

  int far = 0;
  float4 c = pts[0];
  for (int i = 0; i < 512; ++i) {
    if (tid == 0) sel[i] = far;
    uint64_t k[8];
    #pragma unroll
    for (int j = 0; j < 8; ++j) {
      float dx = f_sub(px[j], c.x);
      float dy = f_sub(py[j], c.y);
      float dz = f_sub(pz[j], c.z);
      float d  = f_add(f_add(f_mul(dx,dx), f_mul(dy,dy)), f_mul(dz,dz));
      float nd = fminf(dl[j], d);
      dl[j] = nd;
      k[j] = ((uint64_t)__float_as_uint(nd) << 32) | (uint32_t)~(uint32_t)(tid + 256*j);
    }
    uint64_t a0 = umax64(k[0], k[1]), a1 = umax64(k[2], k[3]);
    uint64_t a2 = umax64(k[4], k[5]), a3 = umax64(k[6], k[7]);
    uint64_t kk = wave_max_bcast(umax64(umax64(a0, a1), umax64(a2, a3)));
    int slot = (i & 1)*4 + w;
    #pragma unroll
    for (int j = 0; j < 8; ++j)
      if (k[j] == kk) {   // exactly one (lane,j) per wave
        wkey[slot] = kk;
        wcrd[slot] = make_float4(px[j], py[j], pz[j], 0.f);
      }
    __syncthreads();
    int sb = (i & 1)*4;
    uint64_t g0 = wkey[sb+0], g1 = wkey[sb+1], g2 = wkey[sb+2], g3 = wkey[sb+3];
    float4 c0 = wcrd[sb+0], c1 = wcrd[sb+1], c2 = wcrd[sb+2], c3 = wcrd[sb+3];
    uint64_t m01 = umax64(g0, g1), m23 = umax64(g2, g3);
    uint64_t gg  = umax64(m01, m23);
    float4 ca = (g0 >= g1) ? c0 : c1;
    float4 cb = (g2 >= g3) ? c2 : c3;
    c = (m01 >= m23) ? ca : cb;
    far = (int)~(uint32_t)gg;
  }
  __syncthreads();

  // Dump level 1; bounce selected points into pts[0..511].
  int p0 = sel[tid], p1 = sel[tid + 256];
  float4 v0 = pts[p0], v1 = pts[p1];
  s1[b*512 + tid]       = p0;
  s1[b*512 + tid + 256] = p1;
  coorq[((size_t)b*3 + 0)*512 + tid] = v0.x;
  coorq[((size_t)b*3 + 1)*512 + tid] = v0.y;
  coorq[((size_t)b*3 + 2)*512 + tid] = v0.z;
  coorq[((size_t)b*3 + 0)*512 + tid + 256] = v1.x;
  coorq[((size_t)b*3 + 1)*512 + tid + 256] = v1.y;
  coorq[((size_t)b*3 + 2)*512 + tid + 256] = v1.z;
  signal_flag(&flags[2]);          // coorq + s1 visible (fence+sync inside)
  pts[tid] = v0; pts[tid + 256] = v1;
  __syncthreads();

  // Level 2: 512 -> 128, single wave, no barriers in loop (validated round 2).
  if (w == 0) {
    float qx[8], qy[8], qz[8], d2[8];
    #pragma unroll
    for (int j = 0; j < 8; ++j) {
      float4 p = pts[lane + 64*j];
      qx[j] = p.x; qy[j] = p.y; qz[j] = p.z; d2[j] = 1e10f;
    }
    int far2 = 0;
    for (int i = 0; i < 128; ++i) {
      if (lane == 0) sel[i] = far2;
      float4 cc = pts[far2];
      uint64_t k[8];
      #pragma unroll
      for (int j = 0; j < 8; ++j) {
        float dx = f_sub(qx[j], cc.x);
        float dy = f_sub(qy[j], cc.y);
        float dz = f_sub(qz[j], cc.z);
        float d  = f_add(f_add(f_mul(dx,dx), f_mul(dy,dy)), f_mul(dz,dz));
        float nd = fminf(d2[j], d);
        d2[j] = nd;
        k[j] = ((uint64_t)__float_as_uint(nd) << 32) | (uint32_t)~(uint32_t)(lane + 64*j);
      }
      uint64_t a0 = umax64(k[0], k[1]), a1 = umax64(k[2], k[3]);
      uint64_t a2 = umax64(k[4], k[5]), a3 = umax64(k[6], k[7]);
      uint64_t kk = wave_max_bcast(umax64(umax64(a0, a1), umax64(a2, a3)));
      far2 = (int)~(uint32_t)kk;
    }
  }
  __syncthreads();
  if (tid < 128) {
    int p = sel[tid];
    float4 v = pts[p];
    s2[b*128 + tid] = p;
    coorq2[((size_t)b*3 + 0)*128 + tid] = v.x;
    coorq2[((size_t)b*3 + 1)*128 + tid] = v.y;
    coorq2[((size_t)b*3 + 2)*128 + tid] = v.z;
    outc[((size_t)b*3 + 0)*128 + tid] = v.x;
    outc[((size_t)b*3 + 1)*128 + tid] = v.y;
    outc[((size_t)b*3 + 2)*128 + tid] = v.z;
  }
  signal_flag(&flags[3]);
}

// ---------------------------------------------------------------------------
// Edge conv pass1 body (numerics unchanged from passing rounds).
// ---------------------------------------------------------------------------
template<int C, int O, int NQ, int NK, bool STORE>
DI void conv_p1_body(
    const float* __restrict__ xqT, int xq_cols, const int* __restrict__ qg,
    const float* __restrict__ xkT, const int* __restrict__ knn_idx,
    const float* __restrict__ w, float* __restrict__ y, float* __restrict__ stats,
    int nt, int g, int b, float* smem)
{
  constexpr int GRP = O/4;
  const int tid = threadIdx.x;
  float* sxq = smem;
  float* sw  = smem + 16*C;
  float* red = sw + GRP*2*C;
  for (int i = tid; i < 16*C; i += 256) {
    int nn = i / C, ci = i % C;
    int q = nt*16 + nn;
    int src = qg ? qg[b*NQ + q] : q;
    sxq[i] = xqT[((size_t)b*xq_cols + src)*C + ci];
  }
  for (int i = tid; i < GRP*2*C; i += 256)
    sw[i] = w[(size_t)g*GRP*2*C + i];
  __syncthreads();

  const int nloc = tid >> 4, kk = tid & 15;
  const int n = nt*16 + nloc;
  const int flat = n*16 + kk;
  const int r = flat / NQ, s = flat % NQ;
  const int nbr = knn_idx[((size_t)b*16 + r)*NQ + s];

  float xqv[C], h1[C];
  {
    const float4* xq4 = (const float4*)(sxq + nloc*C);
    const float4* xk4 = (const float4*)(xkT + ((size_t)b*NK + nbr)*C);
    #pragma unroll
    for (int c4 = 0; c4 < C/4; ++c4) {
      float4 a = xq4[c4], k = xk4[c4];
      xqv[4*c4+0] = a.x; xqv[4*c4+1] = a.y; xqv[4*c4+2] = a.z; xqv[4*c4+3] = a.w;
      h1[4*c4+0] = k.x - a.x; h1[4*c4+1] = k.y - a.y;
      h1[4*c4+2] = k.z - a.z; h1[4*c4+3] = k.w - a.w;
    }
  }
  float lsum = 0.f, lsq = 0.f;
  float* yp = nullptr;
  if constexpr (STORE) yp = y + (((size_t)b*O + (size_t)g*GRP)*NQ + n)*16 + kk;
  for (int o = 0; o < GRP; ++o) {
    const float4* wr = (const float4*)(sw + o*2*C);
    float acc = 0.f;
    #pragma unroll
    for (int c4 = 0; c4 < C/4; ++c4) {
      float4 w4 = wr[c4];
      acc += w4.x*h1[4*c4] + w4.y*h1[4*c4+1] + w4.z*h1[4*c4+2] + w4.w*h1[4*c4+3];
    }
    #pragma unroll
    for (int c4 = 0; c4 < C/4; ++c4) {
      float4 w4 = wr[C/4 + c4];
      acc += w4.x*xqv[4*c4] + w4.y*xqv[4*c4+1] + w4.z*xqv[4*c4+2] + w4.w*xqv[4*c4+3];
    }
    if constexpr (STORE) yp[(size_t)o*NQ*16] = acc;
    lsum += acc; lsq += acc*acc;
  }
  #pragma unroll
  for (int off = 32; off; off >>= 1) {
    lsum += __shfl_xor(lsum, off);
    lsq  += __shfl_xor(lsq, off);
  }
  const int lane = tid & 63, wvid = tid >> 6;
  if (lane == 0) { red[wvid] = lsum; red[4+wvid] = lsq; }
  __syncthreads();
  if (tid == 0) {
    float s0  = (red[0]+red[1]) + (red[2]+red[3]);
    float s1v = (red[4]+red[5]) + (red[6]+red[7]);
    atomicAdd(stats + ((size_t)b*4 + g)*2,     s0);
    atomicAdd(stats + ((size_t)b*4 + g)*2 + 1, s1v);
  }
}

// pass2 body: normalize + affine + lrelu + max over k.
template<int O, int NQ, bool TOUT>
DI void conv_p2_body(const float* __restrict__ y, const float* __restrict__ stats,
                     const float* __restrict__ gamma, const float* __restrict__ beta,
                     float* __restrict__ fout, int task)
{
  int t = task*256 + threadIdx.x;
  if (t < 8*O*NQ) {
    int b = t / (O*NQ);
    int rem = t % (O*NQ);
    int o, n;
    if (TOUT) { o = rem % O; n = rem / O; }
    else      { n = rem % NQ; o = rem / NQ; }
    int g = o / (O/4);
    const float cnt = (float)((O/4) * NQ * 16);
    float s0 = stats[((size_t)b*4 + g)*2], s1v = stats[((size_t)b*4 + g)*2 + 1];
    float mu = s0 / cnt;
    float var = fmaxf(s1v / cnt - mu*mu, 0.f);
    float rs = 1.f / sqrtf(var + 1e-5f);
    float ga = gamma[o], be = beta[o];
    const float4* yp = (const float4*)(y + ((((size_t)b*O + o)*NQ) + n)*16);
    float m = -FLT_MAX;
    #pragma unroll
    for (int i = 0; i < 4; ++i) {
      float4 v4 = yp[i];
      float vv[4] = {v4.x, v4.y, v4.z, v4.w};
      #pragma unroll
      for (int j = 0; j < 4; ++j) {
        float a = (vv[j] - mu)*rs*ga + be;
        a = a >= 0.f ? a : 0.2f*a;
        m = fmaxf(m, a);
      }
    }
    fout[t] = m;
  }
}

// Layer-1 pass2 body: recompute conv + GN + lrelu + max (y1 too big to store).
DI void l1_pass2_body(const float* __restrict__ f0T, const int* __restrict__ idx1,
                      const float* __restrict__ w1, const float* __restrict__ stats,
                      const float* __restrict__ g1, const float* __restrict__ be1,
                      float* __restrict__ f1T, int blk, float* smem)
{
  float* sw = smem;        // 512
  float* sg = smem + 512;  // 32
  float* sb = smem + 544;  // 32
  int tid = threadIdx.x;
  for (int i = tid; i < 512; i += 256) sw[i] = w1[i];
  if (tid < 32) { sg[tid] = g1[tid]; sb[tid] = be1[tid]; }
  __syncthreads();
  int t = blk*256 + tid;
  int b = t >> 11, n = t & 2047;
  float mean[4], rstd[4];
  const float cnt = 8.f*2048.f*16.f;
  #pragma unroll
  for (int g = 0; g < 4; ++g) {
    float mu = stats[(b*4+g)*2] / cnt;
    float var = fmaxf(stats[(b*4+g)*2+1]/cnt - mu*mu, 0.f);
    mean[g] = mu; rstd[g] = 1.f/sqrtf(var + 1e-5f);
  }
  const float4* xqp = (const float4*)(f0T + (size_t)t*8);
  float4 q0 = xqp[0], q1 = xqp[1];
  float xq[8] = {q0.x,q0.y,q0.z,q0.w,q1.x,q1.y,q1.z,q1.w};
  float h[16][8];
  #pragma unroll
  for (int kk = 0; kk < 16; ++kk) {
    int flat = n*16 + kk, r = flat >> 11, s = flat & 2047;
    int nbr = idx1[((b*16 + r) << 11) + s];
    const float4* xkp = (const float4*)(f0T + ((size_t)(b << 11) + nbr)*8);
    float4 k0 = xkp[0], k1 = xkp[1];
    h[kk][0]=k0.x-xq[0]; h[kk][1]=k0.y-xq[1]; h[kk][2]=k0.z-xq[2]; h[kk][3]=k0.w-xq[3];
    h[kk][4]=k1.x-xq[4]; h[kk][5]=k1.y-xq[5]; h[kk][6]=k1.z-xq[6]; h[kk][7]=k1.w-xq[7];
  }
  float* op = f1T + (size_t)t*32;
  for (int o = 0; o < 32; ++o) {
    const float4* wp4 = (const float4*)(sw + o*16);
    float4 wa = wp4[0], wb = wp4[1], wc = wp4[2], wd = wp4[3];
    float base = wc.x*xq[0]+wc.y*xq[1]+wc.z*xq[2]+wc.w*xq[3]
               + wd.x*xq[4]+wd.y*xq[5]+wd.z*xq[6]+wd.w*xq[7];
    int g = o >> 3;
    float mu = mean[g], rs = rstd[g], ga = sg[o], be = sb[o];
    float m = -FLT_MAX;
    #pragma unroll
    for (int kk = 0; kk < 16; ++kk) {
      float acc = base
        + wa.x*h[kk][0]+wa.y*h[kk][1]+wa.z*h[kk][2]+wa.w*h[kk][3]
        + wb.x*h[kk][4]+wb.y*h[kk][5]+wb.z*h[kk][6]+wb.w*h[kk][7];
      float a2 = (acc - mu)*rs*ga + be;
      a2 = a2 >= 0.f ? a2 : 0.2f*a2;
      m = fmaxf(m, a2);
    }
    op[o] = m;
  }
}

// ---------------------------------------------------------------------------
// megaA: grid=256 (all co-resident). Blocks 0-7: FPS. Blocks 8-255: worker
// pool {in_trans, knn1} -> bar -> {L1 stats} -> bar -> {l1_pass2} ->
// {knn2/knn3 after fps-L1 flag, knn4 after fps-L2 flag}.
// ---------------------------------------------------------------------------
__global__ __launch_bounds__(256) void megaA(
    const float* __restrict__ x, const float* __restrict__ w_in, const float* __restrict__ b_in,
    const float* __restrict__ w1, const float* __restrict__ g1, const float* __restrict__ be1,
    float* __restrict__ f0T, int* __restrict__ idx1, float* __restrict__ f1T,
    int* __restrict__ s1, float* __restrict__ coorq,
    int* __restrict__ s2, float* __restrict__ coorq2, float* __restrict__ outc,
    float* __restrict__ stats,
    int* __restrict__ idx2, int* __restrict__ idx3, int* __restrict__ idx4,
    int* flags)
{
  __shared__ char smem_raw[35008] __attribute__((aligned(16)));
  float* smemf = (float*)smem_raw;
  const int bid = blockIdx.x, tid = threadIdx.x;
  const int NW = 248;

  if (bid < 8) {
    fps_body(x, bid, s1, coorq, s2, coorq2, outc, smem_raw, flags);
    return;
  }
  const int wid = bid - 8;

  // P1a: input_trans (64 units of 256 columns)
  if (wid < 64) {
    int t = wid*256 + tid;
    int b = t >> 11, n = t & 2047;
    float x0 = x[((size_t)b*3 + 0)*2048 + n];
    float x1 = x[((size_t)b*3 + 1)*2048 + n];
    float x2 = x[((size_t)b*3 + 2)*2048 + n];
    float* op = f0T + (size_t)t*8;
    #pragma unroll
    for (int o = 0; o < 8; ++o)
      op[o] = w_in[o*3+0]*x0 + w_in[o*3+1]*x1 + w_in[o*3+2]*x2 + b_in[o];
  }
  // P1b: knn1 (4096 tasks of 4 queries, chunked for key-staging reuse)
  {
    int t0 = wid*17, t1 = imin(4096, t0 + 17);
    int curb = -1;
    for (int t = t0; t < t1; ++t) {
      int b = t >> 9;
      if (b != curb) { knn_stage<2048>(x, b, smemf); curb = b; }
      knn_queries<2048>(x, 2048, idx1, b, (t & 511)*4, smemf);
    }
  }
  barrier_arrive_wait(&flags[0], NW);

  // P2: L1 GroupNorm stats (4096 tasks)
  {
    int t0 = wid*17, t1 = imin(4096, t0 + 17);
    for (int t = t0; t < t1; ++t)
      conv_p1_body<8, 32, 2048, 2048, false>(f0T, 2048, nullptr, f0T, idx1, w1,
                                             nullptr, stats,
                                             t & 127, (t >> 7) & 3, t >> 9, smemf);
  }
  barrier_arrive_wait(&flags[1], NW);

  // P3: l1_pass2 (64 tasks)
  if (wid < 64)
    l1_pass2_body(f0T, idx1, w1, stats, g1, be1, f1T, wid, smemf);

  // P4: knn2/knn3 (need fps level-1), knn4 (needs fps level-2)
  if (wid < 112) {
    wait_flag(&flags[2], 8);
    int t0 = wid*10, t1 = imin(1024, t0 + 10);
    int curb = -1;
    for (int t = t0; t < t1; ++t) {
      int b = t >> 7;
      if (b != curb) { knn_stage<2048>(x, b, smemf); curb = b; }
      knn_queries<2048>(coorq, 512, idx2, b, (t & 127)*4, smemf);
    }
  } else if (wid < 224) {
    wait_flag(&flags[2], 8);
    int w2id = wid - 112;
    int t0 = w2id*10, t1 = imin(1024, t0 + 10);
    int curb = -1;
    for (int t = t0; t < t1; ++t) {
      int b = t >> 7;
      if (b != curb) { knn_stage<512>(coorq, b, smemf); curb = b; }
      knn_queries<512>(coorq, 512, idx3, b, (t & 127)*4, smemf);
    }
  } else {
    wait_flag(&flags[3], 8);
    int w3id = wid - 224;
    int t0 = w3id*11, t1 = imin(256, t0 + 11);
    int curb = -1;
    for (int t = t0; t < t1; ++t) {
      int b = t >> 5;
      if (b != curb) { knn_stage<512>(coorq, b, smemf); curb = b; }
      knn_queries<512>(coorq2, 128, idx4, b, (t & 31)*4, smemf);
    }
  }
}

// ---------------------------------------------------------------------------
// megaB: grid=256 (all co-resident). L2 p1 -> bar -> L2 p2 -> bar -> L3 p1 ->
// bar -> L3 p2 -> bar -> L4 p1 -> bar -> L4 p2.
// ---------------------------------------------------------------------------
__global__ __launch_bounds__(256) void megaB(
    const float* __restrict__ f1T, const int* __restrict__ s1, const int* __restrict__ idx2,
    const float* __restrict__ w2, const float* __restrict__ g2, const float* __restrict__ be2,
    float* __restrict__ f2T, const int* __restrict__ idx3,
    const float* __restrict__ w3, const float* __restrict__ g3, const float* __restrict__ be3,
    float* __restrict__ f3T, const int* __restrict__ s2, const int* __restrict__ idx4,
    const float* __restrict__ w4, const float* __restrict__ g4, const float* __restrict__ be4,
    float* __restrict__ f4, float* __restrict__ stats, float* __restrict__ ybuf,
    int* flags)
{
  __shared__ float smem[5160] __attribute__((aligned(16)));
  const int bid = blockIdx.x;

  // L2 p1 (C=32 -> O=64, Nq=512, Nk=2048): 1024 tasks
  for (int t = bid*4; t < bid*4 + 4; ++t)
    conv_p1_body<32, 64, 512, 2048, true>(f1T, 2048, s1, f1T, idx2, w2, ybuf,
                                          stats + 64, t & 31, (t >> 5) & 3, t >> 7, smem);
  barrier_arrive_wait(&flags[8], 256);
  for (int t = bid*4; t < bid*4 + 4; ++t)
    conv_p2_body<64, 512, true>(ybuf, stats + 64, g2, be2, f2T, t);
  barrier_arrive_wait(&flags[9], 256);

  // L3 p1 (C=64 -> O=64, Nq=Nk=512): 1024 tasks
  for (int t = bid*4; t < bid*4 + 4; ++t)
    conv_p1_body<64, 64, 512, 512, true>(f2T, 512, nullptr, f2T, idx3, w3, ybuf,
                                         stats + 128, t & 31, (t >> 5) & 3, t >> 7, smem);
  barrier_arrive_wait(&flags[10], 256);
  for (int t = bid*4; t < bid*4 + 4; ++t)
    conv_p2_body<64, 512, true>(ybuf, stats + 128, g3, be3, f3T, t);
  barrier_arrive_wait(&flags[11], 256);

  // L4 p1 (C=64 -> O=128, Nq=128, Nk=512): 256 tasks
  conv_p1_body<64, 128, 128, 512, true>(f3T, 512, s2, f3T, idx4, w4, ybuf,
                                        stats + 192, bid & 7, (bid >> 3) & 3, bid >> 5, smem);
  barrier_arrive_wait(&flags[12], 256);
  for (int t = bid*2; t < bid*2 + 2; ++t)
    conv_p2_body<128, 128, false>(ybuf, stats + 192, g4, be4, f4, t);
}

// ---------------------------------------------------------------------------
extern "C" void kernel_launch(void* const* d_in, const int* in_sizes, int n_in,
                              void* d_out, int out_size, void* d_ws, size_t ws_size,
                              hipStream_t stream)
{
  (void)in_sizes; (void)n_in; (void)out_size; (void)ws_size;
  const float* x    = (const float*)d_in[0];
  const float* w_in = (const float*)d_in[1];
  const float* b_in = (const float*)d_in[2];
  const float* w1   = (const float*)d_in[3];
  const float* g1   = (const float*)d_in[4];
  const float* be1  = (const float*)d_in[5];
  const float* w2   = (const float*)d_in[6];
  const float* g2   = (const float*)d_in[7];
  const float* be2  = (const float*)d_in[8];
  const float* w3   = (const float*)d_in[9];
  const float* g3   = (const float*)d_in[10];
  const float* be3  = (const float*)d_in[11];
  const float* w4   = (const float*)d_in[12];
  const float* g4   = (const float*)d_in[13];
  const float* be4  = (const float*)d_in[14];

  float* ws = (float*)d_ws;
  float* stats  = ws;                      // 256 floats (4 layers x 8b x 4g x 2)
  int*   flags  = (int*)(ws + 256);        // 32 ints
  float* f0T    = ws + 288;                // [8,2048,8]   -> 131360
  int*   idx1   = (int*)(ws + 131360);     // [8,16,2048]  -> 393504
  float* f1T    = ws + 393504;             // [8,2048,32]  -> 917792
  int*   s1     = (int*)(ws + 917792);     // [8,512]      -> 921888
  float* coorq  = ws + 921888;             // [8,3,512]    -> 934176
  int*   idx2   = (int*)(ws + 934176);     // [8,16,512]   -> 999712
  float* f2T    = ws + 999712;             // [8,512,64]   -> 1261856
  int*   idx3   = (int*)(ws + 1261856);    // [8,16,512]   -> 1327392
  float* f3T    = ws + 1327392;            // [8,512,64]   -> 1589536
  int*   s2     = (int*)(ws + 1589536);    // [8,128]      -> 1590560
  float* coorq2 = ws + 1590560;            // [8,3,128]    -> 1593632
  int*   idx4   = (int*)(ws + 1593632);    // [8,16,128]   -> 1610016
  float* ybuf   = ws + 1610016;            // [8,64,512,16] max

  float* outc = (float*)d_out;             // [8,3,128]
  float* f4   = (float*)d_out + 3072;      // [8,128,128]

  hipMemsetAsync(d_ws, 0, 1152, stream);   // stats + flags

  megaA<<<dim3(256), 256, 0, stream>>>(
      x, w_in, b_in, w1, g1, be1, f0T, idx1, f1T,
      s1, coorq, s2, coorq2, outc, stats, idx2, idx3, idx4, flags);

  megaB<<<dim3(256), 256, 0, stream>>>(
      f1T, s1, idx2, w2, g2, be2, f2T, idx3, w3, g3, be3,
      f3T, s2, idx4, w4, g4, be4, f4, stats, ybuf, flags);
}